// Round 4
// baseline (598.506 us; speedup 1.0000x reference)
//
#include <hip/hip_runtime.h>
#include <stdint.h>

typedef unsigned int       u32;
typedef unsigned long long u64;
typedef unsigned short     u16;

typedef float f32x4 __attribute__((ext_vector_type(4)));
typedef short s16x8 __attribute__((ext_vector_type(8)));

#define AS1 __attribute__((address_space(1)))
#define AS3 __attribute__((address_space(3)))

constexpr int BATCH = 8, SEQ = 2048, DIM = 512, CODES = 8192;
constexpr int MROWS = BATCH * SEQ;          // 16384
constexpr int CAP   = 128;                  // candidate slots per row
#define MARGIN          1.0f                // append margin (~16 sigma of bf16 dot err)
#define RESCORE_MARGIN  0.6f                // exact-rescore filter (~8 sigma)

// ---- ordered-uint encode for float min ----
__device__ __forceinline__ u32 encf(float f) {
    u32 u = __float_as_uint(f);
    return (u & 0x80000000u) ? ~u : (u | 0x80000000u);
}
__device__ __forceinline__ float decf(u32 e) {
    return (e & 0x80000000u) ? __uint_as_float(e & 0x7fffffffu) : __uint_as_float(~e);
}
__device__ __forceinline__ u16 f2bf(float f) {           // RTNE, finite inputs
    u32 u = __float_as_uint(f);
    return (u16)((u + 0x7fffu + ((u >> 16) & 1u)) >> 16);
}

// ---------------- pass 0: fused fp32->bf16 cast + numpy-pairwise-exact row sumsq ----------------
__global__ __launch_bounds__(256) void k_prep(const float* __restrict__ x,
                                              const float* __restrict__ cb,
                                              u16* __restrict__ dx,
                                              u16* __restrict__ dcb,
                                              float* __restrict__ x2,
                                              float* __restrict__ c2,
                                              u32* __restrict__ cnt) {
#pragma clang fp contract(off)
    __shared__ float lp[64 * 133];
    const int t  = threadIdx.x;
    const int bx = blockIdx.x;
    const int gid = bx * 256 + t;
    if (gid < MROWS) cnt[gid] = 0u;

    const float* src; u16* dst; float* dsq; int row0;
    if (bx < 256) { src = x;  dst = dx;  dsq = x2; row0 = bx * 64; }
    else          { src = cb; dst = dcb; dsq = c2; row0 = (bx - 256) * 64; }

    float blk[4];
    for (int p = 0; p < 4; p++) {
#pragma unroll
        for (int k = 0; k < 8; k++) {
            int idx = t + 256 * k;
            int row = idx >> 5, c4 = idx & 31;
            const float* gp = src + (size_t)(row0 + row) * DIM + p * 128 + c4 * 4;
            float4 v = *(const float4*)gp;
            u64 pk = (u64)f2bf(v.x) | ((u64)f2bf(v.y) << 16) |
                     ((u64)f2bf(v.z) << 32) | ((u64)f2bf(v.w) << 48);
            *(u64*)(dst + (size_t)(row0 + row) * DIM + p * 128 + c4 * 4) = pk;
            int la = row * 133 + c4 * 4;
            lp[la] = v.x; lp[la + 1] = v.y; lp[la + 2] = v.z; lp[la + 3] = v.w;
        }
        __syncthreads();
        if (t < 64) {
            const float* q = lp + t * 133;
            float a0 = q[0]*q[0], a1 = q[1]*q[1], a2 = q[2]*q[2], a3 = q[3]*q[3];
            float a4 = q[4]*q[4], a5 = q[5]*q[5], a6 = q[6]*q[6], a7 = q[7]*q[7];
            for (int i = 1; i < 16; i++) {
                const float* r = q + i * 8;
                a0 = a0 + r[0]*r[0]; a1 = a1 + r[1]*r[1];
                a2 = a2 + r[2]*r[2]; a3 = a3 + r[3]*r[3];
                a4 = a4 + r[4]*r[4]; a5 = a5 + r[5]*r[5];
                a6 = a6 + r[6]*r[6]; a7 = a7 + r[7]*r[7];
            }
            blk[p] = ((a0 + a1) + (a2 + a3)) + ((a4 + a5) + (a6 + a7));
        }
        __syncthreads();
    }
    if (t < 64) dsq[row0 + t] = (blk[0] + blk[1]) + (blk[2] + blk[3]);
}

// ---------------- diagnostic: staging path ONLY, amplified 4x ----------------
// Round-0 k_vq's exact staging structure (8 global_load_lds per __syncthreads-iteration,
// double-buffered, implicit vmcnt(0) drain at each barrier) with ds_read/MFMA/epilogue
// removed, run for 32 iterations (= 4 full K-passes). Purpose: price the
// global->L2/L3->LDS path in isolation. Interpretation is pre-committed in the journal:
// k_abl ~ 4x full-kernel time => staging-bound; k_abl ~ 4x (40-90us) => staging healthy.
// Output safety: writes only LDS; the sink write lands in cand[] BEFORE the real k_vq
// repopulates slots [0,cnt) and k_fin reads only i<cnt, so junk is never consumed.
__global__ __launch_bounds__(512, 2) void k_abl(const u16* __restrict__ A,
                                                const u16* __restrict__ B,
                                                uint2* __restrict__ cand) {
    __shared__ u16 lds[2 * 32768];          // same 128 KiB footprint -> same occupancy (1 blk/CU)
    const int t  = threadIdx.x;
    const int bx = blockIdx.x;
    const int row0 = (bx & 63) * 256;
    const int col0 = (bx >> 6) * 256;

    auto stage = [&](int it, int buf) {
        const int kb = it * 64;
#pragma unroll
        for (int p = 0; p < 4; p++) {
            int off = t * 16 + p * 8192;
            int rr  = off >> 7;
            int cc  = (off >> 4) & 7;
            int sc  = (cc ^ (rr & 7)) << 3;
            const u16* ga = A + (size_t)(row0 + rr) * DIM + kb + sc;
            const u16* gb = B + (size_t)(col0 + rr) * DIM + kb + sc;
            __builtin_amdgcn_global_load_lds((const AS1 u32*)ga,
                                             (AS3 u32*)((char*)lds + buf * 65536 + off), 16, 0, 0);
            __builtin_amdgcn_global_load_lds((const AS1 u32*)gb,
                                             (AS3 u32*)((char*)lds + buf * 65536 + 32768 + off), 16, 0, 0);
        }
    };

    stage(0, 0);
    for (int n = 0; n < 32; n++) {          // 4x the real kernel's 8 iterations
        __syncthreads();                    // implicit vmcnt(0) drain, same as round-0 loop
        if (n < 31) stage((n + 1) & 7, (n + 1) & 1);
    }
    volatile u32* lv = (volatile u32*)lds;  // keep LDS live so loads can't be argued dead
    u32 v = lv[t];
    if (v == 0x13572468u) ((u32*)cand)[t] = v;   // sink (slots overwritten by real k_vq)
}

// ---------------- pass 1: 256x256-tile bf16 MFMA GEMM (round-0 exact, best known) ----------------
// grid = 2048 = 64 row-tiles x 32 col-tiles; block = 512 threads (8 waves).
// Wave = 128 rows x 64 cols (acc 8x4 frags). K-loop = 8 iters of BK=64, LDS double-
// buffered (2 x (A 32K | B 32K)); loads for iter n+1 are issued AFTER the barrier
// that opens iter n. XOR-16B-chunk swizzle keeps ds_read_b128 conflict-free.
__global__ __launch_bounds__(512, 2) void k_vq(const u16* __restrict__ A,   // [16384,512] bf16
                                               const u16* __restrict__ B,   // [8192,512] bf16
                                               const float* __restrict__ c2,
                                               u32* __restrict__ cnt,
                                               uint2* __restrict__ cand) {
    __shared__ u16 lds[2 * 32768];          // [buf][A 16K u16 | B 16K u16] = 128 KiB
    __shared__ u32 mrow[256];

    const int t    = threadIdx.x;
    const int wave = t >> 6, lane = t & 63;
    const int lr   = lane & 15, quad = lane >> 4;
    const int bx   = blockIdx.x;
    const int row0 = (bx & 63) * 256;
    const int col0 = (bx >> 6) * 256;
    const int wRow = (wave >> 2) * 128;     // 2 row-bands
    const int wCol = (wave & 3) * 64;       // 4 col-bands
    const int s0   = (quad ^ (lr & 7)) * 8; // swizzled u16 chunk offset, kk=0

    if (t < 256) mrow[t] = 0xFFFFFFFFu;

    f32x4 acc[8][4];
#pragma unroll
    for (int i = 0; i < 8; i++)
#pragma unroll
        for (int j = 0; j < 4; j++) { f32x4 z = {0.f, 0.f, 0.f, 0.f}; acc[i][j] = z; }

    auto stage = [&](int it, int buf) {
        const int kb = it * 64;
#pragma unroll
        for (int p = 0; p < 4; p++) {
            int off = t * 16 + p * 8192;            // byte offset within 32 KiB tile
            int rr  = off >> 7;                     // tile row (128 B/row), 0..255
            int cc  = (off >> 4) & 7;               // LDS chunk position
            int sc  = (cc ^ (rr & 7)) << 3;         // source u16 col (XOR swizzle)
            const u16* ga = A + (size_t)(row0 + rr) * DIM + kb + sc;
            const u16* gb = B + (size_t)(col0 + rr) * DIM + kb + sc;
            __builtin_amdgcn_global_load_lds((const AS1 u32*)ga,
                                             (AS3 u32*)((char*)lds + buf * 65536 + off), 16, 0, 0);
            __builtin_amdgcn_global_load_lds((const AS1 u32*)gb,
                                             (AS3 u32*)((char*)lds + buf * 65536 + 32768 + off), 16, 0, 0);
        }
    };

    stage(0, 0);                              // preamble prefetch
    for (int it = 0; it < 8; it++) {
        const int buf = it & 1;
        __syncthreads();                      // drains buf's loads (issued 1 compute-phase ago)
        if (it < 7) stage(it + 1, buf ^ 1);   // prefetch next AFTER the barrier
        const u16* bufA = lds + buf * 32768;
        const u16* bufB = bufA + 16384;
#pragma unroll
        for (int kk = 0; kk < 2; kk++) {
            const int soff = s0 ^ (kk * 32);  // (chunk ^ 4kk)*8 in u16
            s16x8 af[8], bf[4];
#pragma unroll
            for (int i = 0; i < 8; i++)
                af[i] = *(const s16x8*)&bufA[(wRow + i * 16 + lr) * 64 + soff];
#pragma unroll
            for (int j = 0; j < 4; j++)
                bf[j] = *(const s16x8*)&bufB[(wCol + j * 16 + lr) * 64 + soff];
#pragma unroll
            for (int i = 0; i < 8; i++)
#pragma unroll
                for (int j = 0; j < 4; j++)
                    acc[i][j] = __builtin_amdgcn_mfma_f32_16x16x32_bf16(af[i], bf[j], acc[i][j], 0, 0, 0);
        }
    }

    // ---- epilogue: row-min over this block's 256 cols -> threshold -> margin-append ----
    float c2v[4];
#pragma unroll
    for (int j = 0; j < 4; j++) c2v[j] = c2[col0 + wCol + j * 16 + lr];

#pragma unroll
    for (int i = 0; i < 8; i++) {
#pragma unroll
        for (int r = 0; r < 4; r++) {
            float v0 = c2v[0] - 2.0f * acc[i][0][r];
            float v1 = c2v[1] - 2.0f * acc[i][1][r];
            float v2 = c2v[2] - 2.0f * acc[i][2][r];
            float v3 = c2v[3] - 2.0f * acc[i][3][r];
            float mn = fminf(fminf(v0, v1), fminf(v2, v3));
#pragma unroll
            for (int mask = 1; mask < 16; mask <<= 1)
                mn = fminf(mn, __shfl_xor(mn, mask));
            if (lr == 0) atomicMin(&mrow[wRow + i * 16 + quad * 4 + r], encf(mn));
        }
    }
    __syncthreads();
#pragma unroll
    for (int i = 0; i < 8; i++) {
#pragma unroll
        for (int r = 0; r < 4; r++) {
            const int lrow = wRow + i * 16 + quad * 4 + r;
            const float th = decf(mrow[lrow]) + MARGIN;
            const int grow = row0 + lrow;
#pragma unroll
            for (int j = 0; j < 4; j++) {
                float s = c2v[j] - 2.0f * acc[i][j][r];
                if (s < th) {
                    u32 idx = atomicAdd(&cnt[grow], 1u);
                    if (idx < CAP)
                        cand[(size_t)grow * CAP + idx] =
                            make_uint2(__float_as_uint(s), (u32)(col0 + wCol + j * 16 + lr));
                }
            }
        }
    }
}

// ---------------- pass 2: exact rescore (fp64 dot, np-fp32 pipeline) + gather + PE ----------------
__global__ __launch_bounds__(256) void k_fin(const float* __restrict__ x,
                                             const float* __restrict__ cb,
                                             const float* __restrict__ c2,
                                             const float* __restrict__ x2,
                                             const u32* __restrict__ cnt,
                                             const uint2* __restrict__ cand,
                                             float* __restrict__ out) {
    const int row  = (blockIdx.x * 256 + threadIdx.x) >> 6;   // one wave per row
    const int lane = threadIdx.x & 63;
    int n = (int)cnt[row];
    if (n > CAP) n = CAP;
    if (n < 0) n = 0;
    const uint2* cd = cand + (size_t)row * CAP;

    float m = 3.4028235e38f;
    for (int i = lane; i < n; i += 64) m = fminf(m, __uint_as_float(cd[i].x));
#pragma unroll
    for (int mask = 32; mask; mask >>= 1) m = fminf(m, __shfl_xor(m, mask));
    const float thr = m + RESCORE_MARGIN;

    const float* xr = x + (size_t)row * DIM + lane * 8;
    float4 xv0 = *(const float4*)xr;
    float4 xv1 = *(const float4*)(xr + 4);
    const float x2v = x2[row];

    u64 best = ~0ull;
    for (int i = 0; i < n; i++) {
        uint2 e = cd[i];
        float sa = __uint_as_float(e.x);
        u32 ci = (e.y < (u32)CODES) ? e.y : 0u;                // harden gather index
        if (sa <= thr) {                                       // wave-uniform branch
            const float* cr = cb + (size_t)ci * DIM + lane * 8;
            float4 c0 = *(const float4*)cr;
            float4 c1 = *(const float4*)(cr + 4);
            double d = (double)xv0.x * c0.x + (double)xv0.y * c0.y +
                       (double)xv0.z * c0.z + (double)xv0.w * c0.w +
                       (double)xv1.x * c1.x + (double)xv1.y * c1.y +
                       (double)xv1.z * c1.z + (double)xv1.w * c1.w;
#pragma unroll
            for (int mask = 32; mask; mask >>= 1) d += __shfl_xor(d, mask);
            float dot = (float)d;
            float s32 = (x2v - 2.0f * dot) + c2[ci];           // np fp32 pipeline
            u64 key = ((u64)encf(s32) << 32) | (u64)ci;        // lowest-index tie-break
            best = best < key ? best : key;
        }
    }
    u32 wcol = (u32)(best & 0xffffffffu);
    if (wcol >= (u32)CODES) wcol = 0;                          // unreachable safety

    const float* cw = cb + (size_t)wcol * DIM + lane * 8;
    float4 q0 = *(const float4*)cw;
    float4 q1 = *(const float4*)(cw + 4);
    const int spos = row & (SEQ - 1);
    float pe[8];
#pragma unroll
    for (int ii = 0; ii < 4; ii++) {
        int ipair = lane * 4 + ii;
        float dt  = expf((float)(2 * ipair) * (-0.017988946039035083f)); // ln(1e4)/512
        float ang = (float)spos * dt;
        float sv, cv;
        sincosf(ang, &sv, &cv);
        pe[2 * ii]     = sv;
        pe[2 * ii + 1] = cv;
    }
    float4* op = (float4*)(out + (size_t)row * DIM + lane * 8);
    op[0] = make_float4(q0.x + pe[0], q0.y + pe[1], q0.z + pe[2], q0.w + pe[3]);
    op[1] = make_float4(q1.x + pe[4], q1.y + pe[5], q1.z + pe[6], q1.w + pe[7]);
}

extern "C" void kernel_launch(void* const* d_in, const int* in_sizes, int n_in,
                              void* d_out, int out_size, void* d_ws, size_t ws_size,
                              hipStream_t stream) {
    const float* x  = (const float*)d_in[0];   // [8,2048,512]
    const float* cb = (const float*)d_in[1];   // [8192,512]
    float* out = (float*)d_out;

    char* ws = (char*)d_ws;
    u16*   Abf  = (u16*)ws;                                   // 16 MiB
    u16*   Bbf  = (u16*)(ws + 16777216);                      //  8 MiB
    float* c2   = (float*)(ws + 16777216 + 8388608);          // 32 KiB
    float* x2   = (float*)(ws + 16777216 + 8388608 + 32768);  // 64 KiB
    u32*   cnt  = (u32*)(ws + 16777216 + 8388608 + 32768 + 65536);            // 64 KiB
    uint2* cand = (uint2*)(ws + 16777216 + 8388608 + 32768 + 65536 + 65536);  // 16 MiB

    k_prep<<<dim3(384), dim3(256), 0, stream>>>(x, cb, Abf, Bbf, x2, c2, cnt);
    k_abl<<<dim3(2048), dim3(512), 0, stream>>>(Abf, Bbf, cand);   // diagnostic (see comment)
    k_vq<<<dim3(2048), dim3(512), 0, stream>>>(Abf, Bbf, c2, cnt, cand);
    k_fin<<<dim3(4096), dim3(256), 0, stream>>>(x, cb, c2, x2, cnt, cand, out);
}

// Round 5
// 590.354 us; speedup vs baseline: 1.0138x; 1.0138x over previous
//
#include <hip/hip_runtime.h>
#include <stdint.h>

typedef unsigned int       u32;
typedef unsigned long long u64;
typedef unsigned short     u16;

typedef float f32x4 __attribute__((ext_vector_type(4)));
typedef short s16x8 __attribute__((ext_vector_type(8)));

#define AS1 __attribute__((address_space(1)))
#define AS3 __attribute__((address_space(3)))

constexpr int BATCH = 8, SEQ = 2048, DIM = 512, CODES = 8192;
constexpr int MROWS = BATCH * SEQ;          // 16384
constexpr int CAP   = 128;                  // candidate slots per row
#define MARGIN          1.0f                // append margin (~16 sigma of bf16 dot err)
#define RESCORE_MARGIN  0.6f                // exact-rescore filter (~8 sigma)

// ---- ordered-uint encode for float min ----
__device__ __forceinline__ u32 encf(float f) {
    u32 u = __float_as_uint(f);
    return (u & 0x80000000u) ? ~u : (u | 0x80000000u);
}
__device__ __forceinline__ float decf(u32 e) {
    return (e & 0x80000000u) ? __uint_as_float(e & 0x7fffffffu) : __uint_as_float(~e);
}
__device__ __forceinline__ u16 f2bf(float f) {           // RTNE, finite inputs
    u32 u = __float_as_uint(f);
    return (u16)((u + 0x7fffu + ((u >> 16) & 1u)) >> 16);
}

// ---------------- pass 0: fused fp32->bf16 cast + numpy-pairwise-exact row sumsq ----------------
__global__ __launch_bounds__(256) void k_prep(const float* __restrict__ x,
                                              const float* __restrict__ cb,
                                              u16* __restrict__ dx,
                                              u16* __restrict__ dcb,
                                              float* __restrict__ x2,
                                              float* __restrict__ c2,
                                              u32* __restrict__ cnt) {
#pragma clang fp contract(off)
    __shared__ float lp[64 * 133];
    const int t  = threadIdx.x;
    const int bx = blockIdx.x;
    const int gid = bx * 256 + t;
    if (gid < MROWS) cnt[gid] = 0u;

    const float* src; u16* dst; float* dsq; int row0;
    if (bx < 256) { src = x;  dst = dx;  dsq = x2; row0 = bx * 64; }
    else          { src = cb; dst = dcb; dsq = c2; row0 = (bx - 256) * 64; }

    float blk[4];
    for (int p = 0; p < 4; p++) {
#pragma unroll
        for (int k = 0; k < 8; k++) {
            int idx = t + 256 * k;
            int row = idx >> 5, c4 = idx & 31;
            const float* gp = src + (size_t)(row0 + row) * DIM + p * 128 + c4 * 4;
            float4 v = *(const float4*)gp;
            u64 pk = (u64)f2bf(v.x) | ((u64)f2bf(v.y) << 16) |
                     ((u64)f2bf(v.z) << 32) | ((u64)f2bf(v.w) << 48);
            *(u64*)(dst + (size_t)(row0 + row) * DIM + p * 128 + c4 * 4) = pk;
            int la = row * 133 + c4 * 4;
            lp[la] = v.x; lp[la + 1] = v.y; lp[la + 2] = v.z; lp[la + 3] = v.w;
        }
        __syncthreads();
        if (t < 64) {
            const float* q = lp + t * 133;
            float a0 = q[0]*q[0], a1 = q[1]*q[1], a2 = q[2]*q[2], a3 = q[3]*q[3];
            float a4 = q[4]*q[4], a5 = q[5]*q[5], a6 = q[6]*q[6], a7 = q[7]*q[7];
            for (int i = 1; i < 16; i++) {
                const float* r = q + i * 8;
                a0 = a0 + r[0]*r[0]; a1 = a1 + r[1]*r[1];
                a2 = a2 + r[2]*r[2]; a3 = a3 + r[3]*r[3];
                a4 = a4 + r[4]*r[4]; a5 = a5 + r[5]*r[5];
                a6 = a6 + r[6]*r[6]; a7 = a7 + r[7]*r[7];
            }
            blk[p] = ((a0 + a1) + (a2 + a3)) + ((a4 + a5) + (a6 + a7));
        }
        __syncthreads();
    }
    if (t < 64) dsq[row0 + t] = (blk[0] + blk[1]) + (blk[2] + blk[3]);
}

// ---------------- pass 1: 128x128-tile bf16 MFMA GEMM (m97 structure: TLP > pipelining) ----------------
// Diagnosis (R0-R4): 256^2 tile => 128 KiB LDS + 128 AGPR acc => hard 1 block/CU; all
// schedule variants identical at ~335us because every stall is exposed (no co-resident
// block). k_abl proved staging alone = ~40us; MFMA-at-peak = 55us; the rest was exposed
// latency. Fix = m97's measured mechanism (874-912 TF): 128^2 tile, 64 KiB LDS,
// 256 threads / 4 waves, acc 4x4 (64 AGPR) => 2 blocks/CU; independent blocks overlap
// each other's barrier drains + latencies (m114). Plain __syncthreads loop, prefetch
// issued AFTER the barrier (R0's proven shape), global_load_lds 16B, XOR-chunk swizzle
// (read pattern structurally identical to R0's measured conflict-free one).
// Grid = 8192 = 64 col-tiles (fast) x 128 row-tiles: a concurrent wave of ~512 blocks
// spans all of B (8 MB, L2/L3-shared) x 8 row-bands of A (streamed once).
__global__ __launch_bounds__(256) void k_vq(const u16* __restrict__ A,   // [16384,512] bf16
                                            const u16* __restrict__ B,   // [8192,512] bf16
                                            const float* __restrict__ c2,
                                            u32* __restrict__ cnt,
                                            uint2* __restrict__ cand) {
    __shared__ u16 lds[2 * 16384];          // [buf][A 8K u16 | B 8K u16] = 64 KiB
    __shared__ u32 mrow[128];

    const int t    = threadIdx.x;
    const int wave = t >> 6, lane = t & 63;
    const int lr   = lane & 15, quad = lane >> 4;
    const int bx   = blockIdx.x;
    const int col0 = (bx & 63) * 128;       // col-tile fast (see header)
    const int row0 = (bx >> 6) * 128;
    const int wRow = (wave >> 1) * 64;      // 2x2 wave grid, 64x64 per wave
    const int wCol = (wave & 1) * 64;
    const int s0   = (quad ^ (lr & 7)) * 8; // swizzled u16 chunk offset, kk=0

    if (t < 128) mrow[t] = 0xFFFFFFFFu;

    f32x4 acc[4][4];
#pragma unroll
    for (int i = 0; i < 4; i++)
#pragma unroll
        for (int j = 0; j < 4; j++) { f32x4 z = {0.f, 0.f, 0.f, 0.f}; acc[i][j] = z; }

    auto stage = [&](int it, int buf) {
        const int kb = it * 64;
#pragma unroll
        for (int p = 0; p < 4; p++) {
            int off = t * 16 + p * 4096;            // byte offset within 16 KiB half-tile
            int rr  = off >> 7;                     // tile row (128 B/row), 0..127
            int cc  = (off >> 4) & 7;               // LDS chunk position
            int sc  = (cc ^ (rr & 7)) << 3;         // source u16 col (XOR swizzle)
            const u16* ga = A + (size_t)(row0 + rr) * DIM + kb + sc;
            const u16* gb = B + (size_t)(col0 + rr) * DIM + kb + sc;
            __builtin_amdgcn_global_load_lds((const AS1 u32*)ga,
                                             (AS3 u32*)((char*)lds + buf * 32768 + off), 16, 0, 0);
            __builtin_amdgcn_global_load_lds((const AS1 u32*)gb,
                                             (AS3 u32*)((char*)lds + buf * 32768 + 16384 + off), 16, 0, 0);
        }
    };

    stage(0, 0);                              // preamble prefetch
    for (int it = 0; it < 8; it++) {
        const int buf = it & 1;
        __syncthreads();                      // drains buf's loads (issued 1 compute-phase ago)
        if (it < 7) stage(it + 1, buf ^ 1);   // prefetch next AFTER the barrier
        const u16* bufA = lds + buf * 16384;
        const u16* bufB = bufA + 8192;
#pragma unroll
        for (int kk = 0; kk < 2; kk++) {
            const int soff = s0 ^ (kk * 32);  // (chunk ^ 4kk)*8 in u16
            s16x8 af[4], bf[4];
#pragma unroll
            for (int i = 0; i < 4; i++)
                af[i] = *(const s16x8*)&bufA[(wRow + i * 16 + lr) * 64 + soff];
#pragma unroll
            for (int j = 0; j < 4; j++)
                bf[j] = *(const s16x8*)&bufB[(wCol + j * 16 + lr) * 64 + soff];
#pragma unroll
            for (int i = 0; i < 4; i++)
#pragma unroll
                for (int j = 0; j < 4; j++)
                    acc[i][j] = __builtin_amdgcn_mfma_f32_16x16x32_bf16(af[i], bf[j], acc[i][j], 0, 0, 0);
        }
    }

    // ---- epilogue: row-min over this block's 128 cols -> threshold -> margin-append ----
    // NOTE: threshold is block-LOCAL min + MARGIN => appends are a superset of the true
    // argmin candidates (safe). 64 col-blocks/row now (vs 32): expected appends/row ~64
    // (one near-min per block + rare ties), still well under CAP=128.
    float c2v[4];
#pragma unroll
    for (int j = 0; j < 4; j++) c2v[j] = c2[col0 + wCol + j * 16 + lr];

#pragma unroll
    for (int i = 0; i < 4; i++) {
#pragma unroll
        for (int r = 0; r < 4; r++) {
            float v0 = c2v[0] - 2.0f * acc[i][0][r];
            float v1 = c2v[1] - 2.0f * acc[i][1][r];
            float v2 = c2v[2] - 2.0f * acc[i][2][r];
            float v3 = c2v[3] - 2.0f * acc[i][3][r];
            float mn = fminf(fminf(v0, v1), fminf(v2, v3));
#pragma unroll
            for (int mask = 1; mask < 16; mask <<= 1)
                mn = fminf(mn, __shfl_xor(mn, mask));
            if (lr == 0) atomicMin(&mrow[wRow + i * 16 + quad * 4 + r], encf(mn));
        }
    }
    __syncthreads();
#pragma unroll
    for (int i = 0; i < 4; i++) {
#pragma unroll
        for (int r = 0; r < 4; r++) {
            const int lrow = wRow + i * 16 + quad * 4 + r;
            const float th = decf(mrow[lrow]) + MARGIN;
            const int grow = row0 + lrow;
#pragma unroll
            for (int j = 0; j < 4; j++) {
                float s = c2v[j] - 2.0f * acc[i][j][r];
                if (s < th) {
                    u32 idx = atomicAdd(&cnt[grow], 1u);
                    if (idx < CAP)
                        cand[(size_t)grow * CAP + idx] =
                            make_uint2(__float_as_uint(s), (u32)(col0 + wCol + j * 16 + lr));
                }
            }
        }
    }
}

// ---------------- pass 2: exact rescore (fp64 dot, np-fp32 pipeline) + gather + PE ----------------
__global__ __launch_bounds__(256) void k_fin(const float* __restrict__ x,
                                             const float* __restrict__ cb,
                                             const float* __restrict__ c2,
                                             const float* __restrict__ x2,
                                             const u32* __restrict__ cnt,
                                             const uint2* __restrict__ cand,
                                             float* __restrict__ out) {
    const int row  = (blockIdx.x * 256 + threadIdx.x) >> 6;   // one wave per row
    const int lane = threadIdx.x & 63;
    int n = (int)cnt[row];
    if (n > CAP) n = CAP;
    if (n < 0) n = 0;
    const uint2* cd = cand + (size_t)row * CAP;

    float m = 3.4028235e38f;
    for (int i = lane; i < n; i += 64) m = fminf(m, __uint_as_float(cd[i].x));
#pragma unroll
    for (int mask = 32; mask; mask >>= 1) m = fminf(m, __shfl_xor(m, mask));
    const float thr = m + RESCORE_MARGIN;

    const float* xr = x + (size_t)row * DIM + lane * 8;
    float4 xv0 = *(const float4*)xr;
    float4 xv1 = *(const float4*)(xr + 4);
    const float x2v = x2[row];

    u64 best = ~0ull;
    for (int i = 0; i < n; i++) {
        uint2 e = cd[i];
        float sa = __uint_as_float(e.x);
        u32 ci = (e.y < (u32)CODES) ? e.y : 0u;                // harden gather index
        if (sa <= thr) {                                       // wave-uniform branch
            const float* cr = cb + (size_t)ci * DIM + lane * 8;
            float4 c0 = *(const float4*)cr;
            float4 c1 = *(const float4*)(cr + 4);
            double d = (double)xv0.x * c0.x + (double)xv0.y * c0.y +
                       (double)xv0.z * c0.z + (double)xv0.w * c0.w +
                       (double)xv1.x * c1.x + (double)xv1.y * c1.y +
                       (double)xv1.z * c1.z + (double)xv1.w * c1.w;
#pragma unroll
            for (int mask = 32; mask; mask >>= 1) d += __shfl_xor(d, mask);
            float dot = (float)d;
            float s32 = (x2v - 2.0f * dot) + c2[ci];           // np fp32 pipeline
            u64 key = ((u64)encf(s32) << 32) | (u64)ci;        // lowest-index tie-break
            best = best < key ? best : key;
        }
    }
    u32 wcol = (u32)(best & 0xffffffffu);
    if (wcol >= (u32)CODES) wcol = 0;                          // unreachable safety

    const float* cw = cb + (size_t)wcol * DIM + lane * 8;
    float4 q0 = *(const float4*)cw;
    float4 q1 = *(const float4*)(cw + 4);
    const int spos = row & (SEQ - 1);
    float pe[8];
#pragma unroll
    for (int ii = 0; ii < 4; ii++) {
        int ipair = lane * 4 + ii;
        float dt  = expf((float)(2 * ipair) * (-0.017988946039035083f)); // ln(1e4)/512
        float ang = (float)spos * dt;
        float sv, cv;
        sincosf(ang, &sv, &cv);
        pe[2 * ii]     = sv;
        pe[2 * ii + 1] = cv;
    }
    float4* op = (float4*)(out + (size_t)row * DIM + lane * 8);
    op[0] = make_float4(q0.x + pe[0], q0.y + pe[1], q0.z + pe[2], q0.w + pe[3]);
    op[1] = make_float4(q1.x + pe[4], q1.y + pe[5], q1.z + pe[6], q1.w + pe[7]);
}

extern "C" void kernel_launch(void* const* d_in, const int* in_sizes, int n_in,
                              void* d_out, int out_size, void* d_ws, size_t ws_size,
                              hipStream_t stream) {
    const float* x  = (const float*)d_in[0];   // [8,2048,512]
    const float* cb = (const float*)d_in[1];   // [8192,512]
    float* out = (float*)d_out;

    char* ws = (char*)d_ws;
    u16*   Abf  = (u16*)ws;                                   // 16 MiB
    u16*   Bbf  = (u16*)(ws + 16777216);                      //  8 MiB
    float* c2   = (float*)(ws + 16777216 + 8388608);          // 32 KiB
    float* x2   = (float*)(ws + 16777216 + 8388608 + 32768);  // 64 KiB
    u32*   cnt  = (u32*)(ws + 16777216 + 8388608 + 32768 + 65536);            // 64 KiB
    uint2* cand = (uint2*)(ws + 16777216 + 8388608 + 32768 + 65536 + 65536);  // 16 MiB

    k_prep<<<dim3(384), dim3(256), 0, stream>>>(x, cb, Abf, Bbf, x2, c2, cnt);
    k_vq<<<dim3(8192), dim3(256), 0, stream>>>(Abf, Bbf, c2, cnt, cand);
    k_fin<<<dim3(4096), dim3(256), 0, stream>>>(x, cb, c2, x2, cnt, cand, out);
}

// Round 7
// 545.785 us; speedup vs baseline: 1.0966x; 1.0817x over previous
//
#include <hip/hip_runtime.h>
#include <stdint.h>

typedef unsigned int       u32;
typedef unsigned long long u64;
typedef unsigned short     u16;

typedef float f32x4 __attribute__((ext_vector_type(4)));
typedef short s16x8 __attribute__((ext_vector_type(8)));

#define AS1 __attribute__((address_space(1)))
#define AS3 __attribute__((address_space(3)))

constexpr int BATCH = 8, SEQ = 2048, DIM = 512, CODES = 8192;
constexpr int MROWS = BATCH * SEQ;          // 16384
constexpr int CAP   = 128;                  // candidate slots per row
#define MARGIN          1.0f                // append margin (~16 sigma of bf16 dot err)
#define RESCORE_MARGIN  0.6f                // exact-rescore filter (~8 sigma)

// ---- ordered-uint encode for float min ----
__device__ __forceinline__ u32 encf(float f) {
    u32 u = __float_as_uint(f);
    return (u & 0x80000000u) ? ~u : (u | 0x80000000u);
}
__device__ __forceinline__ float decf(u32 e) {
    return (e & 0x80000000u) ? __uint_as_float(e & 0x7fffffffu) : __uint_as_float(~e);
}
__device__ __forceinline__ u16 f2bf(float f) {           // RTNE, finite inputs
    u32 u = __float_as_uint(f);
    return (u16)((u + 0x7fffu + ((u >> 16) & 1u)) >> 16);
}

// ---------------- pass 0: fused fp32->bf16 cast + numpy-pairwise-exact row sumsq ----------------
__global__ __launch_bounds__(256) void k_prep(const float* __restrict__ x,
                                              const float* __restrict__ cb,
                                              u16* __restrict__ dx,
                                              u16* __restrict__ dcb,
                                              float* __restrict__ x2,
                                              float* __restrict__ c2,
                                              u32* __restrict__ cnt) {
#pragma clang fp contract(off)
    __shared__ float lp[64 * 133];
    const int t  = threadIdx.x;
    const int bx = blockIdx.x;
    const int gid = bx * 256 + t;
    if (gid < MROWS) cnt[gid] = 0u;

    const float* src; u16* dst; float* dsq; int row0;
    if (bx < 256) { src = x;  dst = dx;  dsq = x2; row0 = bx * 64; }
    else          { src = cb; dst = dcb; dsq = c2; row0 = (bx - 256) * 64; }

    float blk[4];
    for (int p = 0; p < 4; p++) {
#pragma unroll
        for (int k = 0; k < 8; k++) {
            int idx = t + 256 * k;
            int row = idx >> 5, c4 = idx & 31;
            const float* gp = src + (size_t)(row0 + row) * DIM + p * 128 + c4 * 4;
            float4 v = *(const float4*)gp;
            u64 pk = (u64)f2bf(v.x) | ((u64)f2bf(v.y) << 16) |
                     ((u64)f2bf(v.z) << 32) | ((u64)f2bf(v.w) << 48);
            *(u64*)(dst + (size_t)(row0 + row) * DIM + p * 128 + c4 * 4) = pk;
            int la = row * 133 + c4 * 4;
            lp[la] = v.x; lp[la + 1] = v.y; lp[la + 2] = v.z; lp[la + 3] = v.w;
        }
        __syncthreads();
        if (t < 64) {
            const float* q = lp + t * 133;
            float a0 = q[0]*q[0], a1 = q[1]*q[1], a2 = q[2]*q[2], a3 = q[3]*q[3];
            float a4 = q[4]*q[4], a5 = q[5]*q[5], a6 = q[6]*q[6], a7 = q[7]*q[7];
            for (int i = 1; i < 16; i++) {
                const float* r = q + i * 8;
                a0 = a0 + r[0]*r[0]; a1 = a1 + r[1]*r[1];
                a2 = a2 + r[2]*r[2]; a3 = a3 + r[3]*r[3];
                a4 = a4 + r[4]*r[4]; a5 = a5 + r[5]*r[5];
                a6 = a6 + r[6]*r[6]; a7 = a7 + r[7]*r[7];
            }
            blk[p] = ((a0 + a1) + (a2 + a3)) + ((a4 + a5) + (a6 + a7));
        }
        __syncthreads();
    }
    if (t < 64) dsq[row0 + t] = (blk[0] + blk[1]) + (blk[2] + blk[3]);
}

// ---------------- diagnostic: R0 K-loop EXACT, epilogue stubbed (prices K-loop vs epilogue) ----------------
// Identical staging + ds_read + MFMA structure, grid, LDS footprint, launch bounds as k_vq.
// Epilogue replaced by an asm keep-alive on the acc reduction (rule #17: no DCE, no writes).
// Reading: k_noepi time = dur_us_total - 436us (dur_us is the per-iteration sum).
__global__ __launch_bounds__(512, 2) void k_noepi(const u16* __restrict__ A,
                                                  const u16* __restrict__ B,
                                                  const float* __restrict__ c2) {
    __shared__ u16 lds[2 * 32768];
    __shared__ u32 mrow[256];

    const int t    = threadIdx.x;
    const int wave = t >> 6, lane = t & 63;
    const int lr   = lane & 15, quad = lane >> 4;
    const int bx   = blockIdx.x;
    const int row0 = (bx & 63) * 256;
    const int col0 = (bx >> 6) * 256;
    const int wRow = (wave >> 2) * 128;
    const int wCol = (wave & 3) * 64;
    const int s0   = (quad ^ (lr & 7)) * 8;

    if (t < 256) mrow[t] = 0xFFFFFFFFu;

    f32x4 acc[8][4];
#pragma unroll
    for (int i = 0; i < 8; i++)
#pragma unroll
        for (int j = 0; j < 4; j++) { f32x4 z = {0.f, 0.f, 0.f, 0.f}; acc[i][j] = z; }

    auto stage = [&](int it, int buf) {
        const int kb = it * 64;
#pragma unroll
        for (int p = 0; p < 4; p++) {
            int off = t * 16 + p * 8192;
            int rr  = off >> 7;
            int cc  = (off >> 4) & 7;
            int sc  = (cc ^ (rr & 7)) << 3;
            const u16* ga = A + (size_t)(row0 + rr) * DIM + kb + sc;
            const u16* gb = B + (size_t)(col0 + rr) * DIM + kb + sc;
            __builtin_amdgcn_global_load_lds((const AS1 u32*)ga,
                                             (AS3 u32*)((char*)lds + buf * 65536 + off), 16, 0, 0);
            __builtin_amdgcn_global_load_lds((const AS1 u32*)gb,
                                             (AS3 u32*)((char*)lds + buf * 65536 + 32768 + off), 16, 0, 0);
        }
    };

    stage(0, 0);
    for (int it = 0; it < 8; it++) {
        const int buf = it & 1;
        __syncthreads();
        if (it < 7) stage(it + 1, buf ^ 1);
        const u16* bufA = lds + buf * 32768;
        const u16* bufB = bufA + 16384;
#pragma unroll
        for (int kk = 0; kk < 2; kk++) {
            const int soff = s0 ^ (kk * 32);
            s16x8 af[8], bf[4];
#pragma unroll
            for (int i = 0; i < 8; i++)
                af[i] = *(const s16x8*)&bufA[(wRow + i * 16 + lr) * 64 + soff];
#pragma unroll
            for (int j = 0; j < 4; j++)
                bf[j] = *(const s16x8*)&bufB[(wCol + j * 16 + lr) * 64 + soff];
#pragma unroll
            for (int i = 0; i < 8; i++)
#pragma unroll
                for (int j = 0; j < 4; j++)
                    acc[i][j] = __builtin_amdgcn_mfma_f32_16x16x32_bf16(af[i], bf[j], acc[i][j], 0, 0, 0);
        }
    }

    // keep-alive stub: depends on every acc element + mrow; emits no memory traffic
    float s = c2[col0 + wCol + lr] + (float)mrow[t & 255];
#pragma unroll
    for (int i = 0; i < 8; i++)
#pragma unroll
        for (int j = 0; j < 4; j++)
#pragma unroll
            for (int r = 0; r < 4; r++) s += acc[i][j][r];
    asm volatile("" :: "v"(s));
}

// ---------------- pass 1: 256x256-tile bf16 MFMA GEMM (round-0 exact, best known) ----------------
__global__ __launch_bounds__(512, 2) void k_vq(const u16* __restrict__ A,   // [16384,512] bf16
                                               const u16* __restrict__ B,   // [8192,512] bf16
                                               const float* __restrict__ c2,
                                               u32* __restrict__ cnt,
                                               uint2* __restrict__ cand) {
    __shared__ u16 lds[2 * 32768];          // [buf][A 16K u16 | B 16K u16] = 128 KiB
    __shared__ u32 mrow[256];

    const int t    = threadIdx.x;
    const int wave = t >> 6, lane = t & 63;
    const int lr   = lane & 15, quad = lane >> 4;
    const int bx   = blockIdx.x;
    const int row0 = (bx & 63) * 256;
    const int col0 = (bx >> 6) * 256;
    const int wRow = (wave >> 2) * 128;     // 2 row-bands
    const int wCol = (wave & 3) * 64;       // 4 col-bands
    const int s0   = (quad ^ (lr & 7)) * 8; // swizzled u16 chunk offset, kk=0

    if (t < 256) mrow[t] = 0xFFFFFFFFu;

    f32x4 acc[8][4];
#pragma unroll
    for (int i = 0; i < 8; i++)
#pragma unroll
        for (int j = 0; j < 4; j++) { f32x4 z = {0.f, 0.f, 0.f, 0.f}; acc[i][j] = z; }

    auto stage = [&](int it, int buf) {
        const int kb = it * 64;
#pragma unroll
        for (int p = 0; p < 4; p++) {
            int off = t * 16 + p * 8192;            // byte offset within 32 KiB tile
            int rr  = off >> 7;                     // tile row (128 B/row), 0..255
            int cc  = (off >> 4) & 7;               // LDS chunk position
            int sc  = (cc ^ (rr & 7)) << 3;         // source u16 col (XOR swizzle)
            const u16* ga = A + (size_t)(row0 + rr) * DIM + kb + sc;
            const u16* gb = B + (size_t)(col0 + rr) * DIM + kb + sc;
            __builtin_amdgcn_global_load_lds((const AS1 u32*)ga,
                                             (AS3 u32*)((char*)lds + buf * 65536 + off), 16, 0, 0);
            __builtin_amdgcn_global_load_lds((const AS1 u32*)gb,
                                             (AS3 u32*)((char*)lds + buf * 65536 + 32768 + off), 16, 0, 0);
        }
    };

    stage(0, 0);                              // preamble prefetch
    for (int it = 0; it < 8; it++) {
        const int buf = it & 1;
        __syncthreads();                      // drains buf's loads (issued 1 compute-phase ago)
        if (it < 7) stage(it + 1, buf ^ 1);   // prefetch next AFTER the barrier
        const u16* bufA = lds + buf * 32768;
        const u16* bufB = bufA + 16384;
#pragma unroll
        for (int kk = 0; kk < 2; kk++) {
            const int soff = s0 ^ (kk * 32);  // (chunk ^ 4kk)*8 in u16
            s16x8 af[8], bf[4];
#pragma unroll
            for (int i = 0; i < 8; i++)
                af[i] = *(const s16x8*)&bufA[(wRow + i * 16 + lr) * 64 + soff];
#pragma unroll
            for (int j = 0; j < 4; j++)
                bf[j] = *(const s16x8*)&bufB[(wCol + j * 16 + lr) * 64 + soff];
#pragma unroll
            for (int i = 0; i < 8; i++)
#pragma unroll
                for (int j = 0; j < 4; j++)
                    acc[i][j] = __builtin_amdgcn_mfma_f32_16x16x32_bf16(af[i], bf[j], acc[i][j], 0, 0, 0);
        }
    }

    // ---- epilogue: row-min over this block's 256 cols -> threshold -> margin-append ----
    float c2v[4];
#pragma unroll
    for (int j = 0; j < 4; j++) c2v[j] = c2[col0 + wCol + j * 16 + lr];

#pragma unroll
    for (int i = 0; i < 8; i++) {
#pragma unroll
        for (int r = 0; r < 4; r++) {
            float v0 = c2v[0] - 2.0f * acc[i][0][r];
            float v1 = c2v[1] - 2.0f * acc[i][1][r];
            float v2 = c2v[2] - 2.0f * acc[i][2][r];
            float v3 = c2v[3] - 2.0f * acc[i][3][r];
            float mn = fminf(fminf(v0, v1), fminf(v2, v3));
#pragma unroll
            for (int mask = 1; mask < 16; mask <<= 1)
                mn = fminf(mn, __shfl_xor(mn, mask));
            if (lr == 0) atomicMin(&mrow[wRow + i * 16 + quad * 4 + r], encf(mn));
        }
    }
    __syncthreads();
#pragma unroll
    for (int i = 0; i < 8; i++) {
#pragma unroll
        for (int r = 0; r < 4; r++) {
            const int lrow = wRow + i * 16 + quad * 4 + r;
            const float th = decf(mrow[lrow]) + MARGIN;
            const int grow = row0 + lrow;
#pragma unroll
            for (int j = 0; j < 4; j++) {
                float s = c2v[j] - 2.0f * acc[i][j][r];
                if (s < th) {
                    u32 idx = atomicAdd(&cnt[grow], 1u);
                    if (idx < CAP)
                        cand[(size_t)grow * CAP + idx] =
                            make_uint2(__float_as_uint(s), (u32)(col0 + wCol + j * 16 + lr));
                }
            }
        }
    }
}

// ---------------- pass 2: exact rescore (fp64 dot, np-fp32 pipeline) + gather + PE ----------------
__global__ __launch_bounds__(256) void k_fin(const float* __restrict__ x,
                                             const float* __restrict__ cb,
                                             const float* __restrict__ c2,
                                             const float* __restrict__ x2,
                                             const u32* __restrict__ cnt,
                                             const uint2* __restrict__ cand,
                                             float* __restrict__ out) {
    const int row  = (blockIdx.x * 256 + threadIdx.x) >> 6;   // one wave per row
    const int lane = threadIdx.x & 63;
    int n = (int)cnt[row];
    if (n > CAP) n = CAP;
    if (n < 0) n = 0;
    const uint2* cd = cand + (size_t)row * CAP;

    float m = 3.4028235e38f;
    for (int i = lane; i < n; i += 64) m = fminf(m, __uint_as_float(cd[i].x));
#pragma unroll
    for (int mask = 32; mask; mask >>= 1) m = fminf(m, __shfl_xor(m, mask));
    const float thr = m + RESCORE_MARGIN;

    const float* xr = x + (size_t)row * DIM + lane * 8;
    float4 xv0 = *(const float4*)xr;
    float4 xv1 = *(const float4*)(xr + 4);
    const float x2v = x2[row];

    u64 best = ~0ull;
    for (int i = 0; i < n; i++) {
        uint2 e = cd[i];
        float sa = __uint_as_float(e.x);
        u32 ci = (e.y < (u32)CODES) ? e.y : 0u;                // harden gather index
        if (sa <= thr) {                                       // wave-uniform branch
            const float* cr = cb + (size_t)ci * DIM + lane * 8;
            float4 c0 = *(const float4*)cr;
            float4 c1 = *(const float4*)(cr + 4);
            double d = (double)xv0.x * c0.x + (double)xv0.y * c0.y +
                       (double)xv0.z * c0.z + (double)xv0.w * c0.w +
                       (double)xv1.x * c1.x + (double)xv1.y * c1.y +
                       (double)xv1.z * c1.z + (double)xv1.w * c1.w;
#pragma unroll
            for (int mask = 32; mask; mask >>= 1) d += __shfl_xor(d, mask);
            float dot = (float)d;
            float s32 = (x2v - 2.0f * dot) + c2[ci];           // np fp32 pipeline
            u64 key = ((u64)encf(s32) << 32) | (u64)ci;        // lowest-index tie-break
            best = best < key ? best : key;
        }
    }
    u32 wcol = (u32)(best & 0xffffffffu);
    if (wcol >= (u32)CODES) wcol = 0;                          // unreachable safety

    const float* cw = cb + (size_t)wcol * DIM + lane * 8;
    float4 q0 = *(const float4*)cw;
    float4 q1 = *(const float4*)(cw + 4);
    const int spos = row & (SEQ - 1);
    float pe[8];
#pragma unroll
    for (int ii = 0; ii < 4; ii++) {
        int ipair = lane * 4 + ii;
        float dt  = expf((float)(2 * ipair) * (-0.017988946039035083f)); // ln(1e4)/512
        float ang = (float)spos * dt;
        float sv, cv;
        sincosf(ang, &sv, &cv);
        pe[2 * ii]     = sv;
        pe[2 * ii + 1] = cv;
    }
    float4* op = (float4*)(out + (size_t)row * DIM + lane * 8);
    op[0] = make_float4(q0.x + pe[0], q0.y + pe[1], q0.z + pe[2], q0.w + pe[3]);
    op[1] = make_float4(q1.x + pe[4], q1.y + pe[5], q1.z + pe[6], q1.w + pe[7]);
}

extern "C" void kernel_launch(void* const* d_in, const int* in_sizes, int n_in,
                              void* d_out, int out_size, void* d_ws, size_t ws_size,
                              hipStream_t stream) {
    const float* x  = (const float*)d_in[0];   // [8,2048,512]
    const float* cb = (const float*)d_in[1];   // [8192,512]
    float* out = (float*)d_out;

    char* ws = (char*)d_ws;
    u16*   Abf  = (u16*)ws;                                   // 16 MiB
    u16*   Bbf  = (u16*)(ws + 16777216);                      //  8 MiB
    float* c2   = (float*)(ws + 16777216 + 8388608);          // 32 KiB
    float* x2   = (float*)(ws + 16777216 + 8388608 + 32768);  // 64 KiB
    u32*   cnt  = (u32*)(ws + 16777216 + 8388608 + 32768 + 65536);            // 64 KiB
    uint2* cand = (uint2*)(ws + 16777216 + 8388608 + 32768 + 65536 + 65536);  // 16 MiB

    k_prep<<<dim3(384), dim3(256), 0, stream>>>(x, cb, Abf, Bbf, x2, c2, cnt);
    k_noepi<<<dim3(2048), dim3(512), 0, stream>>>(Abf, Bbf, c2);   // diagnostic (reads only)
    k_vq<<<dim3(2048), dim3(512), 0, stream>>>(Abf, Bbf, c2, cnt, cand);
    k_fin<<<dim3(4096), dim3(256), 0, stream>>>(x, cb, c2, x2, cnt, cand, out);
}

// Round 8
// 343.851 us; speedup vs baseline: 1.7406x; 1.5873x over previous
//
#include <hip/hip_runtime.h>
#include <stdint.h>

typedef unsigned int       u32;
typedef unsigned long long u64;
typedef unsigned short     u16;

typedef float f32x4 __attribute__((ext_vector_type(4)));
typedef short s16x8 __attribute__((ext_vector_type(8)));

#define AS1 __attribute__((address_space(1)))
#define AS3 __attribute__((address_space(3)))

constexpr int BATCH = 8, SEQ = 2048, DIM = 512, CODES = 8192;
constexpr int MROWS = BATCH * SEQ;          // 16384
constexpr int NBLK  = 32;                   // col-blocks per row (8192/256)
constexpr int SLOTS = 6;                    // candidate slots per (row, col-block)
#define MARGIN          1.0f                // append margin (~16 sigma of bf16 dot err)
#define RESCORE_MARGIN  0.6f                // exact-rescore filter (~8 sigma)

// ---- ordered-uint encode for float min (k_fin tie-break key) ----
__device__ __forceinline__ u32 encf(float f) {
    u32 u = __float_as_uint(f);
    return (u & 0x80000000u) ? ~u : (u | 0x80000000u);
}
__device__ __forceinline__ u16 f2bf(float f) {           // RTNE, finite inputs
    u32 u = __float_as_uint(f);
    return (u16)((u + 0x7fffu + ((u >> 16) & 1u)) >> 16);
}

// ---------------- pass 0: fused fp32->bf16 cast + numpy-pairwise-exact row sumsq ----------------
__global__ __launch_bounds__(256) void k_prep(const float* __restrict__ x,
                                              const float* __restrict__ cb,
                                              u16* __restrict__ dx,
                                              u16* __restrict__ dcb,
                                              float* __restrict__ x2,
                                              float* __restrict__ c2) {
#pragma clang fp contract(off)
    __shared__ float lp[64 * 133];
    const int t  = threadIdx.x;
    const int bx = blockIdx.x;

    const float* src; u16* dst; float* dsq; int row0;
    if (bx < 256) { src = x;  dst = dx;  dsq = x2; row0 = bx * 64; }
    else          { src = cb; dst = dcb; dsq = c2; row0 = (bx - 256) * 64; }

    float blk[4];
    for (int p = 0; p < 4; p++) {
#pragma unroll
        for (int k = 0; k < 8; k++) {
            int idx = t + 256 * k;
            int row = idx >> 5, c4 = idx & 31;
            const float* gp = src + (size_t)(row0 + row) * DIM + p * 128 + c4 * 4;
            float4 v = *(const float4*)gp;
            u64 pk = (u64)f2bf(v.x) | ((u64)f2bf(v.y) << 16) |
                     ((u64)f2bf(v.z) << 32) | ((u64)f2bf(v.w) << 48);
            *(u64*)(dst + (size_t)(row0 + row) * DIM + p * 128 + c4 * 4) = pk;
            int la = row * 133 + c4 * 4;
            lp[la] = v.x; lp[la + 1] = v.y; lp[la + 2] = v.z; lp[la + 3] = v.w;
        }
        __syncthreads();
        if (t < 64) {
            const float* q = lp + t * 133;
            float a0 = q[0]*q[0], a1 = q[1]*q[1], a2 = q[2]*q[2], a3 = q[3]*q[3];
            float a4 = q[4]*q[4], a5 = q[5]*q[5], a6 = q[6]*q[6], a7 = q[7]*q[7];
            for (int i = 1; i < 16; i++) {
                const float* r = q + i * 8;
                a0 = a0 + r[0]*r[0]; a1 = a1 + r[1]*r[1];
                a2 = a2 + r[2]*r[2]; a3 = a3 + r[3]*r[3];
                a4 = a4 + r[4]*r[4]; a5 = a5 + r[5]*r[5];
                a6 = a6 + r[6]*r[6]; a7 = a7 + r[7]*r[7];
            }
            blk[p] = ((a0 + a1) + (a2 + a3)) + ((a4 + a5) + (a6 + a7));
        }
        __syncthreads();
    }
    if (t < 64) dsq[row0 + t] = (blk[0] + blk[1]) + (blk[2] + blk[3]);
}

// ---------------- pass 1: 256x256-tile bf16 MFMA GEMM, atomic-free dense epilogue ----------------
// K-loop byte-identical to the verified R0 baseline (110us alone, k_noepi R7 ablation).
// Epilogue REWRITTEN (was 223us = 67% of k_vq, R7 measurement):
//   old: 128 ds_bpermute + 32 LDS atomicMin + 128 divergent returning-global-atomicAdd/thread
//   new: (1) per-thread min-over-j -> smin[256][68] in the dead tile LDS (stride 68 -> 2-way
//        bank aliasing = free, m136); (2) 2 threads/row serial f32x4 reduce + 1 shuffle ->
//        rmin[256]; (3) candidates (s < rmin+MARGIN) staged via LDS atomicAdd (~1/row);
//        (4) published DENSE: bcnt[row][blk], bcand[row][blk][6] -- plain stores, exactly one
//        writer per (row,blk), ZERO global atomics, no zero-init needed (fully overwritten).
// Candidate-count safety: E[qualifying cols within +1.0 of block-min | 256 Gaussian-d2 samples,
// spread ~55] ~= 1.03; P(>6) is astronomically small (and the old CAP=128/row drop had the
// same risk class). k_fin reads only k < bcnt.
__global__ __launch_bounds__(512, 2) void k_vq(const u16* __restrict__ A,   // [16384,512] bf16
                                               const u16* __restrict__ B,   // [8192,512] bf16
                                               const float* __restrict__ c2,
                                               u32* __restrict__ bcnt,
                                               uint2* __restrict__ bcand) {
    __shared__ u16 lds[2 * 32768];          // K-loop: [buf][A 16K u16 | B 16K u16] = 128 KiB
                                            // epilogue scratch (after loop): see offsets below
    const int t    = threadIdx.x;
    const int wave = t >> 6, lane = t & 63;
    const int lr   = lane & 15, quad = lane >> 4;
    const int bx   = blockIdx.x;
    const int row0 = (bx & 63) * 256;
    const int col0 = (bx >> 6) * 256;
    const int bcol = bx >> 6;               // col-block index 0..31
    const int wRow = (wave >> 2) * 128;     // 2 row-bands
    const int wCol = (wave & 3) * 64;       // 4 col-bands
    const int s0   = (quad ^ (lr & 7)) * 8; // swizzled u16 chunk offset, kk=0

    f32x4 acc[8][4];
#pragma unroll
    for (int i = 0; i < 8; i++)
#pragma unroll
        for (int j = 0; j < 4; j++) { f32x4 z = {0.f, 0.f, 0.f, 0.f}; acc[i][j] = z; }

    auto stage = [&](int it, int buf) {
        const int kb = it * 64;
#pragma unroll
        for (int p = 0; p < 4; p++) {
            int off = t * 16 + p * 8192;            // byte offset within 32 KiB tile
            int rr  = off >> 7;                     // tile row (128 B/row), 0..255
            int cc  = (off >> 4) & 7;               // LDS chunk position
            int sc  = (cc ^ (rr & 7)) << 3;         // source u16 col (XOR swizzle)
            const u16* ga = A + (size_t)(row0 + rr) * DIM + kb + sc;
            const u16* gb = B + (size_t)(col0 + rr) * DIM + kb + sc;
            __builtin_amdgcn_global_load_lds((const AS1 u32*)ga,
                                             (AS3 u32*)((char*)lds + buf * 65536 + off), 16, 0, 0);
            __builtin_amdgcn_global_load_lds((const AS1 u32*)gb,
                                             (AS3 u32*)((char*)lds + buf * 65536 + 32768 + off), 16, 0, 0);
        }
    };

    stage(0, 0);                              // preamble prefetch
    for (int it = 0; it < 8; it++) {
        const int buf = it & 1;
        __syncthreads();                      // drains buf's loads (issued 1 compute-phase ago)
        if (it < 7) stage(it + 1, buf ^ 1);   // prefetch next AFTER the barrier
        const u16* bufA = lds + buf * 32768;
        const u16* bufB = bufA + 16384;
#pragma unroll
        for (int kk = 0; kk < 2; kk++) {
            const int soff = s0 ^ (kk * 32);  // (chunk ^ 4kk)*8 in u16
            s16x8 af[8], bf[4];
#pragma unroll
            for (int i = 0; i < 8; i++)
                af[i] = *(const s16x8*)&bufA[(wRow + i * 16 + lr) * 64 + soff];
#pragma unroll
            for (int j = 0; j < 4; j++)
                bf[j] = *(const s16x8*)&bufB[(wCol + j * 16 + lr) * 64 + soff];
#pragma unroll
            for (int i = 0; i < 8; i++)
#pragma unroll
                for (int j = 0; j < 4; j++)
                    acc[i][j] = __builtin_amdgcn_mfma_f32_16x16x32_bf16(af[i], bf[j], acc[i][j], 0, 0, 0);
        }
    }

    __syncthreads();                          // all waves done reading tile LDS -> safe to reuse

    // scratch layout in the 128 KiB lds array (all offsets 16B-aligned):
    float* smin   = (float*)lds;                             // [256][68] = 69632 B
    u32*   ccnt   = (u32*)((char*)lds + 69632);              // [256]     =  1024 B
    uint2* cstage = (uint2*)((char*)lds + 70656);            // [256][6]  = 12288 B
    float* rmin   = (float*)((char*)lds + 82944);            // [256]     =  1024 B

    float c2v[4];
#pragma unroll
    for (int j = 0; j < 4; j++) c2v[j] = c2[col0 + wCol + j * 16 + lr];

    // ---- phase 1: per-thread min over j -> smin[row][(wave&3)*16 + lr] (one writer/slot) ----
#pragma unroll
    for (int i = 0; i < 8; i++) {
#pragma unroll
        for (int r = 0; r < 4; r++) {
            float v0 = c2v[0] - 2.0f * acc[i][0][r];
            float v1 = c2v[1] - 2.0f * acc[i][1][r];
            float v2 = c2v[2] - 2.0f * acc[i][2][r];
            float v3 = c2v[3] - 2.0f * acc[i][3][r];
            const int lrow = wRow + i * 16 + quad * 4 + r;
            smin[lrow * 68 + (wave & 3) * 16 + lr] = fminf(fminf(v0, v1), fminf(v2, v3));
        }
    }
    if (t < 256) ccnt[t] = 0u;
    __syncthreads();

    // ---- phase 2: row-min reduce (2 threads/row, f32x4 serial + 1 shuffle) ----
    {
        const int row = t >> 1, h = t & 1;
        const f32x4* p4 = (const f32x4*)(smin + row * 68 + h * 32);   // 272B row stride: 16B-aligned
        f32x4 m4 = p4[0];
#pragma unroll
        for (int k = 1; k < 8; k++) {
            f32x4 v = p4[k];
            m4[0] = fminf(m4[0], v[0]); m4[1] = fminf(m4[1], v[1]);
            m4[2] = fminf(m4[2], v[2]); m4[3] = fminf(m4[3], v[3]);
        }
        float m = fminf(fminf(m4[0], m4[1]), fminf(m4[2], m4[3]));
        m = fminf(m, __shfl_xor(m, 1));
        if (h == 0) rmin[row] = m;
    }
    __syncthreads();

    // ---- phase 3: stage candidates (s < rowmin + MARGIN) via cheap LDS atomics ----
#pragma unroll
    for (int i = 0; i < 8; i++) {
#pragma unroll
        for (int r = 0; r < 4; r++) {
            const int lrow = wRow + i * 16 + quad * 4 + r;
            const float th = rmin[lrow] + MARGIN;
#pragma unroll
            for (int j = 0; j < 4; j++) {
                float s = c2v[j] - 2.0f * acc[i][j][r];
                if (s < th) {
                    u32 idx = atomicAdd(&ccnt[lrow], 1u);
                    if (idx < (u32)SLOTS)
                        cstage[lrow * SLOTS + idx] =
                            make_uint2(__float_as_uint(s), (u32)(col0 + wCol + j * 16 + lr));
                }
            }
        }
    }
    __syncthreads();

    // ---- phase 4: publish dense (plain stores, unique writer per (row, col-block)) ----
    if (t < 256) {
        u32 c = ccnt[t]; if (c > (u32)SLOTS) c = (u32)SLOTS;
        const size_t gi = (size_t)(row0 + t) * NBLK + bcol;
        bcnt[gi] = c;
#pragma unroll
        for (int k = 0; k < SLOTS; k++)
            if ((u32)k < c) bcand[gi * SLOTS + k] = cstage[t * SLOTS + k];
    }
}

// ---------------- pass 2: dense-scan min + exact rescore (fp64 dot) + gather + PE ----------------
__global__ __launch_bounds__(256) void k_fin(const float* __restrict__ x,
                                             const float* __restrict__ cb,
                                             const float* __restrict__ c2,
                                             const float* __restrict__ x2,
                                             const u32* __restrict__ bcnt,
                                             const uint2* __restrict__ bcand,
                                             float* __restrict__ out) {
    __shared__ u32  wcnt[4];
    __shared__ uint2 wbuf[4][64];
    const int tid  = threadIdx.x;
    const int wid  = tid >> 6;
    const int lane = tid & 63;
    const int row  = (blockIdx.x * 256 + tid) >> 6;           // one wave per row
    if (lane == 0) wcnt[wid] = 0u;

    // lanes 0..31 each own one col-block: load its <=6 entries, local min
    float m = 3.4028235e38f;
    uint2 ent[SLOTS];
    int c = 0;
    if (lane < NBLK) {
        const size_t gi = (size_t)row * NBLK + lane;
        u32 cc = bcnt[gi]; c = (cc > (u32)SLOTS) ? SLOTS : (int)cc;
#pragma unroll
        for (int k = 0; k < SLOTS; k++) {                     // predicated full unroll (rule #20)
            if (k < c) {
                ent[k] = bcand[gi * SLOTS + k];
                m = fminf(m, __uint_as_float(ent[k].x));
            }
        }
    }
#pragma unroll
    for (int mask = 32; mask; mask >>= 1) m = fminf(m, __shfl_xor(m, mask));
    const float thr = m + RESCORE_MARGIN;

    // stage within-margin entries to the wave's LDS list (same-wave in-order LDS => no barrier)
    if (lane < NBLK) {
#pragma unroll
        for (int k = 0; k < SLOTS; k++) {
            if (k < c && __uint_as_float(ent[k].x) <= thr) {
                u32 pos = atomicAdd(&wcnt[wid], 1u);
                if (pos < 64u) wbuf[wid][pos] = ent[k];
            }
        }
    }
    int n = (int)wcnt[wid]; if (n > 64) n = 64;

    const float* xr = x + (size_t)row * DIM + lane * 8;
    float4 xv0 = *(const float4*)xr;
    float4 xv1 = *(const float4*)(xr + 4);
    const float x2v = x2[row];

    u64 best = ~0ull;
    for (int i = 0; i < n; i++) {                             // wave-uniform, all pre-filtered
        uint2 e = wbuf[wid][i];
        u32 ci = (e.y < (u32)CODES) ? e.y : 0u;               // harden gather index
        const float* cr = cb + (size_t)ci * DIM + lane * 8;
        float4 c0 = *(const float4*)cr;
        float4 c1 = *(const float4*)(cr + 4);
        double d = (double)xv0.x * c0.x + (double)xv0.y * c0.y +
                   (double)xv0.z * c0.z + (double)xv0.w * c0.w +
                   (double)xv1.x * c1.x + (double)xv1.y * c1.y +
                   (double)xv1.z * c1.z + (double)xv1.w * c1.w;
#pragma unroll
        for (int mask = 32; mask; mask >>= 1) d += __shfl_xor(d, mask);
        float dot = (float)d;
        float s32 = (x2v - 2.0f * dot) + c2[ci];              // np fp32 pipeline
        u64 key = ((u64)encf(s32) << 32) | (u64)ci;           // lowest-index tie-break
        best = best < key ? best : key;
    }
    u32 wcol = (u32)(best & 0xffffffffu);
    if (wcol >= (u32)CODES) wcol = 0;                         // unreachable safety (n >= 1)

    const float* cw = cb + (size_t)wcol * DIM + lane * 8;
    float4 q0 = *(const float4*)cw;
    float4 q1 = *(const float4*)(cw + 4);
    const int spos = row & (SEQ - 1);
    float pe[8];
#pragma unroll
    for (int ii = 0; ii < 4; ii++) {
        int ipair = lane * 4 + ii;
        float dt  = expf((float)(2 * ipair) * (-0.017988946039035083f)); // ln(1e4)/512
        float ang = (float)spos * dt;
        float sv, cv;
        sincosf(ang, &sv, &cv);
        pe[2 * ii]     = sv;
        pe[2 * ii + 1] = cv;
    }
    float4* op = (float4*)(out + (size_t)row * DIM + lane * 8);
    op[0] = make_float4(q0.x + pe[0], q0.y + pe[1], q0.z + pe[2], q0.w + pe[3]);
    op[1] = make_float4(q1.x + pe[4], q1.y + pe[5], q1.z + pe[6], q1.w + pe[7]);
}

extern "C" void kernel_launch(void* const* d_in, const int* in_sizes, int n_in,
                              void* d_out, int out_size, void* d_ws, size_t ws_size,
                              hipStream_t stream) {
    const float* x  = (const float*)d_in[0];   // [8,2048,512]
    const float* cb = (const float*)d_in[1];   // [8192,512]
    float* out = (float*)d_out;

    char* ws = (char*)d_ws;
    u16*   Abf   = (u16*)ws;                                   // 16 MiB
    u16*   Bbf   = (u16*)(ws + 16777216);                      //  8 MiB
    float* c2    = (float*)(ws + 25165824);                    // 32 KiB
    float* x2    = (float*)(ws + 25198592);                    // 64 KiB
    u32*   bcnt  = (u32*)(ws + 25264128);                      // 16384*32*4 = 2 MiB
    uint2* bcand = (uint2*)(ws + 27361280);                    // 16384*32*6*8 = 24 MiB
    // total ws use: ~50.1 MiB (< previous 57.8 MiB layout)

    k_prep<<<dim3(384), dim3(256), 0, stream>>>(x, cb, Abf, Bbf, x2, c2);
    k_vq<<<dim3(2048), dim3(512), 0, stream>>>(Abf, Bbf, c2, bcnt, bcand);
    k_fin<<<dim3(4096), dim3(256), 0, stream>>>(x, cb, c2, x2, bcnt, bcand, out);
}

// Round 9
// 343.301 us; speedup vs baseline: 1.7434x; 1.0016x over previous
//
#include <hip/hip_runtime.h>
#include <stdint.h>

typedef unsigned int       u32;
typedef unsigned long long u64;
typedef unsigned short     u16;

typedef float f32x4 __attribute__((ext_vector_type(4)));
typedef short s16x8 __attribute__((ext_vector_type(8)));

#define AS1 __attribute__((address_space(1)))
#define AS3 __attribute__((address_space(3)))

constexpr int BATCH = 8, SEQ = 2048, DIM = 512, CODES = 8192;
constexpr int MROWS = BATCH * SEQ;          // 16384
constexpr int NBLK  = 32;                   // col-blocks per row (8192/256)
constexpr int SLOTS = 6;                    // candidate slots per (row, col-block)
#define MARGIN          1.0f                // append margin (~16 sigma of bf16 dot err)
#define RESCORE_MARGIN  0.6f                // exact-rescore filter (~8 sigma)
#define SENTINEL        0x7f800000u         // +INF bits: auto-loses min, fails <=thr filter

// ---- ordered-uint encode for float min (k_fin tie-break key) ----
__device__ __forceinline__ u32 encf(float f) {
    u32 u = __float_as_uint(f);
    return (u & 0x80000000u) ? ~u : (u | 0x80000000u);
}
__device__ __forceinline__ u16 f2bf(float f) {           // RTNE, finite inputs
    u32 u = __float_as_uint(f);
    return (u16)((u + 0x7fffu + ((u >> 16) & 1u)) >> 16);
}

// ---------------- pass 0: fused fp32->bf16 cast + numpy-pairwise-exact row sumsq ----------------
__global__ __launch_bounds__(256) void k_prep(const float* __restrict__ x,
                                              const float* __restrict__ cb,
                                              u16* __restrict__ dx,
                                              u16* __restrict__ dcb,
                                              float* __restrict__ x2,
                                              float* __restrict__ c2) {
#pragma clang fp contract(off)
    __shared__ float lp[64 * 133];
    const int t  = threadIdx.x;
    const int bx = blockIdx.x;

    const float* src; u16* dst; float* dsq; int row0;
    if (bx < 256) { src = x;  dst = dx;  dsq = x2; row0 = bx * 64; }
    else          { src = cb; dst = dcb; dsq = c2; row0 = (bx - 256) * 64; }

    float blk[4];
    for (int p = 0; p < 4; p++) {
#pragma unroll
        for (int k = 0; k < 8; k++) {
            int idx = t + 256 * k;
            int row = idx >> 5, c4 = idx & 31;
            const float* gp = src + (size_t)(row0 + row) * DIM + p * 128 + c4 * 4;
            float4 v = *(const float4*)gp;
            u64 pk = (u64)f2bf(v.x) | ((u64)f2bf(v.y) << 16) |
                     ((u64)f2bf(v.z) << 32) | ((u64)f2bf(v.w) << 48);
            *(u64*)(dst + (size_t)(row0 + row) * DIM + p * 128 + c4 * 4) = pk;
            int la = row * 133 + c4 * 4;
            lp[la] = v.x; lp[la + 1] = v.y; lp[la + 2] = v.z; lp[la + 3] = v.w;
        }
        __syncthreads();
        if (t < 64) {
            const float* q = lp + t * 133;
            float a0 = q[0]*q[0], a1 = q[1]*q[1], a2 = q[2]*q[2], a3 = q[3]*q[3];
            float a4 = q[4]*q[4], a5 = q[5]*q[5], a6 = q[6]*q[6], a7 = q[7]*q[7];
            for (int i = 1; i < 16; i++) {
                const float* r = q + i * 8;
                a0 = a0 + r[0]*r[0]; a1 = a1 + r[1]*r[1];
                a2 = a2 + r[2]*r[2]; a3 = a3 + r[3]*r[3];
                a4 = a4 + r[4]*r[4]; a5 = a5 + r[5]*r[5];
                a6 = a6 + r[6]*r[6]; a7 = a7 + r[7]*r[7];
            }
            blk[p] = ((a0 + a1) + (a2 + a3)) + ((a4 + a5) + (a6 + a7));
        }
        __syncthreads();
    }
    if (t < 64) dsq[row0 + t] = (blk[0] + blk[1]) + (blk[2] + blk[3]);
}

// ---------------- pass 1: 256x256-tile bf16 MFMA GEMM, coalesced transposed publish ----------------
// K-loop byte-identical to the verified R0 baseline (110us alone, R7 k_noepi ablation).
// R8 post-mortem: epilogue compute is cheap, but the [row][bcol] publish layout made every
// store a partial-line RFO (FETCH 65->186 MB, WRITE 74->209 MB) and evicted the A/B L2
// panels, slowing the K-loop itself. Fix: TRANSPOSED layout bc[bcol][row][SLOTS] -- each
// block writes 256 consecutive 48B records = one 12 KB contiguous burst (full lines, no
// RFO, no bcnt array: empty slots carry an +INF sentinel that loses every min and fails
// the <=thr filter in k_fin). Phases 1-3 unchanged (complete: every margin-qualifier from
// acc is appended; SLOTS=6 drop risk identical to R8).
__global__ __launch_bounds__(512, 2) void k_vq(const u16* __restrict__ A,   // [16384,512] bf16
                                               const u16* __restrict__ B,   // [8192,512] bf16
                                               const float* __restrict__ c2,
                                               uint2* __restrict__ bc) {    // [NBLK][MROWS][SLOTS]
    __shared__ u16 lds[2 * 32768];          // K-loop: [buf][A 16K u16 | B 16K u16] = 128 KiB
                                            // epilogue scratch (after loop): see offsets below
    const int t    = threadIdx.x;
    const int wave = t >> 6, lane = t & 63;
    const int lr   = lane & 15, quad = lane >> 4;
    const int bx   = blockIdx.x;
    const int row0 = (bx & 63) * 256;
    const int col0 = (bx >> 6) * 256;
    const int bcol = bx >> 6;               // col-block index 0..31
    const int wRow = (wave >> 2) * 128;     // 2 row-bands
    const int wCol = (wave & 3) * 64;       // 4 col-bands
    const int s0   = (quad ^ (lr & 7)) * 8; // swizzled u16 chunk offset, kk=0

    f32x4 acc[8][4];
#pragma unroll
    for (int i = 0; i < 8; i++)
#pragma unroll
        for (int j = 0; j < 4; j++) { f32x4 z = {0.f, 0.f, 0.f, 0.f}; acc[i][j] = z; }

    auto stage = [&](int it, int buf) {
        const int kb = it * 64;
#pragma unroll
        for (int p = 0; p < 4; p++) {
            int off = t * 16 + p * 8192;            // byte offset within 32 KiB tile
            int rr  = off >> 7;                     // tile row (128 B/row), 0..255
            int cc  = (off >> 4) & 7;               // LDS chunk position
            int sc  = (cc ^ (rr & 7)) << 3;         // source u16 col (XOR swizzle)
            const u16* ga = A + (size_t)(row0 + rr) * DIM + kb + sc;
            const u16* gb = B + (size_t)(col0 + rr) * DIM + kb + sc;
            __builtin_amdgcn_global_load_lds((const AS1 u32*)ga,
                                             (AS3 u32*)((char*)lds + buf * 65536 + off), 16, 0, 0);
            __builtin_amdgcn_global_load_lds((const AS1 u32*)gb,
                                             (AS3 u32*)((char*)lds + buf * 65536 + 32768 + off), 16, 0, 0);
        }
    };

    stage(0, 0);                              // preamble prefetch
    for (int it = 0; it < 8; it++) {
        const int buf = it & 1;
        __syncthreads();                      // drains buf's loads (issued 1 compute-phase ago)
        if (it < 7) stage(it + 1, buf ^ 1);   // prefetch next AFTER the barrier
        const u16* bufA = lds + buf * 32768;
        const u16* bufB = bufA + 16384;
#pragma unroll
        for (int kk = 0; kk < 2; kk++) {
            const int soff = s0 ^ (kk * 32);  // (chunk ^ 4kk)*8 in u16
            s16x8 af[8], bf[4];
#pragma unroll
            for (int i = 0; i < 8; i++)
                af[i] = *(const s16x8*)&bufA[(wRow + i * 16 + lr) * 64 + soff];
#pragma unroll
            for (int j = 0; j < 4; j++)
                bf[j] = *(const s16x8*)&bufB[(wCol + j * 16 + lr) * 64 + soff];
#pragma unroll
            for (int i = 0; i < 8; i++)
#pragma unroll
                for (int j = 0; j < 4; j++)
                    acc[i][j] = __builtin_amdgcn_mfma_f32_16x16x32_bf16(af[i], bf[j], acc[i][j], 0, 0, 0);
        }
    }

    __syncthreads();                          // all waves done reading tile LDS -> safe to reuse

    // scratch layout in the 128 KiB lds array (all offsets 16B-aligned):
    float* smin   = (float*)lds;                             // [256][68] = 69632 B
    u32*   ccnt   = (u32*)((char*)lds + 69632);              // [256]     =  1024 B
    uint2* cstage = (uint2*)((char*)lds + 70656);            // [256][6]  = 12288 B
    float* rmin   = (float*)((char*)lds + 82944);            // [256]     =  1024 B

    float c2v[4];
#pragma unroll
    for (int j = 0; j < 4; j++) c2v[j] = c2[col0 + wCol + j * 16 + lr];

    // ---- phase 1: per-thread min over j -> smin[row][(wave&3)*16 + lr] (one writer/slot) ----
#pragma unroll
    for (int i = 0; i < 8; i++) {
#pragma unroll
        for (int r = 0; r < 4; r++) {
            float v0 = c2v[0] - 2.0f * acc[i][0][r];
            float v1 = c2v[1] - 2.0f * acc[i][1][r];
            float v2 = c2v[2] - 2.0f * acc[i][2][r];
            float v3 = c2v[3] - 2.0f * acc[i][3][r];
            const int lrow = wRow + i * 16 + quad * 4 + r;
            smin[lrow * 68 + (wave & 3) * 16 + lr] = fminf(fminf(v0, v1), fminf(v2, v3));
        }
    }
    if (t < 256) ccnt[t] = 0u;
    __syncthreads();

    // ---- phase 2: row-min reduce (2 threads/row, f32x4 serial + 1 shuffle) ----
    {
        const int row = t >> 1, h = t & 1;
        const f32x4* p4 = (const f32x4*)(smin + row * 68 + h * 32);   // 272B row stride: 16B-aligned
        f32x4 m4 = p4[0];
#pragma unroll
        for (int k = 1; k < 8; k++) {
            f32x4 v = p4[k];
            m4[0] = fminf(m4[0], v[0]); m4[1] = fminf(m4[1], v[1]);
            m4[2] = fminf(m4[2], v[2]); m4[3] = fminf(m4[3], v[3]);
        }
        float m = fminf(fminf(m4[0], m4[1]), fminf(m4[2], m4[3]));
        m = fminf(m, __shfl_xor(m, 1));
        if (h == 0) rmin[row] = m;
    }
    __syncthreads();

    // ---- phase 3: stage candidates (s < rowmin + MARGIN) via cheap LDS atomics ----
#pragma unroll
    for (int i = 0; i < 8; i++) {
#pragma unroll
        for (int r = 0; r < 4; r++) {
            const int lrow = wRow + i * 16 + quad * 4 + r;
            const float th = rmin[lrow] + MARGIN;
#pragma unroll
            for (int j = 0; j < 4; j++) {
                float s = c2v[j] - 2.0f * acc[i][j][r];
                if (s < th) {
                    u32 idx = atomicAdd(&ccnt[lrow], 1u);
                    if (idx < (u32)SLOTS)
                        cstage[lrow * SLOTS + idx] =
                            make_uint2(__float_as_uint(s), (u32)(col0 + wCol + j * 16 + lr));
                }
            }
        }
    }
    __syncthreads();

    // ---- phase 4: publish, transposed + sentinel-padded (one 12 KB contiguous burst/block) ----
    if (t < 256) {
        u32 c = ccnt[t]; if (c > (u32)SLOTS) c = (u32)SLOTS;
        uint2 outv[SLOTS];
#pragma unroll
        for (int k = 0; k < SLOTS; k++)
            outv[k] = ((u32)k < c) ? cstage[t * SLOTS + k] : make_uint2(SENTINEL, 0u);
        uint2* dst = bc + ((size_t)bcol * MROWS + row0 + t) * SLOTS;   // 48B, 16B-aligned
#pragma unroll
        for (int k = 0; k < SLOTS; k++) dst[k] = outv[k];              // merges to 3x dwordx4
    }
}

// ---------------- pass 2: dense-scan min + exact rescore (fp64 dot) + gather + PE ----------------
__global__ __launch_bounds__(256) void k_fin(const float* __restrict__ x,
                                             const float* __restrict__ cb,
                                             const float* __restrict__ c2,
                                             const float* __restrict__ x2,
                                             const uint2* __restrict__ bc,
                                             float* __restrict__ out) {
    __shared__ u32  wcnt[4];
    __shared__ uint2 wbuf[4][64];
    const int tid  = threadIdx.x;
    const int wid  = tid >> 6;
    const int lane = tid & 63;
    const int row  = (blockIdx.x * 256 + tid) >> 6;           // one wave per row
    if (lane == 0) wcnt[wid] = 0u;

    // lanes 0..31 each own one col-block: 48B sentinel-padded record, local min
    float m = 3.4028235e38f;
    uint2 ent[SLOTS];
    if (lane < NBLK) {
        const uint2* src = bc + ((size_t)lane * MROWS + row) * SLOTS;
#pragma unroll
        for (int k = 0; k < SLOTS; k++) {
            ent[k] = src[k];                                  // INF sentinels are neutral
            m = fminf(m, __uint_as_float(ent[k].x));
        }
    }
#pragma unroll
    for (int mask = 32; mask; mask >>= 1) m = fminf(m, __shfl_xor(m, mask));
    const float thr = m + RESCORE_MARGIN;

    // stage within-margin entries to the wave's LDS list (same-wave in-order LDS => no barrier)
    if (lane < NBLK) {
#pragma unroll
        for (int k = 0; k < SLOTS; k++) {
            if (__uint_as_float(ent[k].x) <= thr) {           // sentinel INF always fails
                u32 pos = atomicAdd(&wcnt[wid], 1u);
                if (pos < 64u) wbuf[wid][pos] = ent[k];
            }
        }
    }
    int n = (int)wcnt[wid]; if (n > 64) n = 64;

    const float* xr = x + (size_t)row * DIM + lane * 8;
    float4 xv0 = *(const float4*)xr;
    float4 xv1 = *(const float4*)(xr + 4);
    const float x2v = x2[row];

    u64 best = ~0ull;
    for (int i = 0; i < n; i++) {                             // wave-uniform, all pre-filtered
        uint2 e = wbuf[wid][i];
        u32 ci = (e.y < (u32)CODES) ? e.y : 0u;               // harden gather index
        const float* cr = cb + (size_t)ci * DIM + lane * 8;
        float4 c0 = *(const float4*)cr;
        float4 c1 = *(const float4*)(cr + 4);
        double d = (double)xv0.x * c0.x + (double)xv0.y * c0.y +
                   (double)xv0.z * c0.z + (double)xv0.w * c0.w +
                   (double)xv1.x * c1.x + (double)xv1.y * c1.y +
                   (double)xv1.z * c1.z + (double)xv1.w * c1.w;
#pragma unroll
        for (int mask = 32; mask; mask >>= 1) d += __shfl_xor(d, mask);
        float dot = (float)d;
        float s32 = (x2v - 2.0f * dot) + c2[ci];              // np fp32 pipeline
        u64 key = ((u64)encf(s32) << 32) | (u64)ci;           // lowest-index tie-break
        best = best < key ? best : key;
    }
    u32 wcol = (u32)(best & 0xffffffffu);
    if (wcol >= (u32)CODES) wcol = 0;                         // unreachable safety (n >= 1)

    const float* cw = cb + (size_t)wcol * DIM + lane * 8;
    float4 q0 = *(const float4*)cw;
    float4 q1 = *(const float4*)(cw + 4);
    const int spos = row & (SEQ - 1);
    float pe[8];
#pragma unroll
    for (int ii = 0; ii < 4; ii++) {
        int ipair = lane * 4 + ii;
        float dt  = expf((float)(2 * ipair) * (-0.017988946039035083f)); // ln(1e4)/512
        float ang = (float)spos * dt;
        float sv, cv;
        sincosf(ang, &sv, &cv);
        pe[2 * ii]     = sv;
        pe[2 * ii + 1] = cv;
    }
    float4* op = (float4*)(out + (size_t)row * DIM + lane * 8);
    op[0] = make_float4(q0.x + pe[0], q0.y + pe[1], q0.z + pe[2], q0.w + pe[3]);
    op[1] = make_float4(q1.x + pe[4], q1.y + pe[5], q1.z + pe[6], q1.w + pe[7]);
}

extern "C" void kernel_launch(void* const* d_in, const int* in_sizes, int n_in,
                              void* d_out, int out_size, void* d_ws, size_t ws_size,
                              hipStream_t stream) {
    const float* x  = (const float*)d_in[0];   // [8,2048,512]
    const float* cb = (const float*)d_in[1];   // [8192,512]
    float* out = (float*)d_out;

    char* ws = (char*)d_ws;
    u16*   Abf = (u16*)ws;                                   // 16 MiB
    u16*   Bbf = (u16*)(ws + 16777216);                      //  8 MiB
    float* c2  = (float*)(ws + 25165824);                    // 32 KiB
    float* x2  = (float*)(ws + 25198592);                    // 64 KiB
    uint2* bc  = (uint2*)(ws + 25264128);                    // [32][16384][6] uint2 = 24 MiB
    // total ws use: ~48.1 MiB

    k_prep<<<dim3(384), dim3(256), 0, stream>>>(x, cb, Abf, Bbf, x2, c2);
    k_vq<<<dim3(2048), dim3(512), 0, stream>>>(Abf, Bbf, c2, bc);
    k_fin<<<dim3(4096), dim3(256), 0, stream>>>(x, cb, c2, x2, bc, out);
}